// Round 7
// baseline (1605.033 us; speedup 1.0000x reference)
//
#include <hip/hip_runtime.h>
#include <math.h>

#define NTHREADS 256
#define IN_C 128
#define HID 64
#define OUT_C 40
#define N_LAYERS 8
#define ALPHA 0.1f
#define BN_EPS 1e-5f

typedef float f32x4 __attribute__((ext_vector_type(4)));
typedef _Float16 f16;
typedef _Float16 f16x4 __attribute__((ext_vector_type(4)));

__device__ __forceinline__ f32x4 ld4(const float* p) { return *(const f32x4*)p; }

// fp16 row load + widen
__device__ __forceinline__ f32x4 ldh4(const f16* p) {
  f16x4 v = *(const f16x4*)p;
  return __builtin_convertvector(v, f32x4);
}

// fused BN + ReLU: relu(v*k1 + k2). Layer 0 uses identity k1=1,k2=0.
__device__ __forceinline__ f32x4 bnrelu(f32x4 v, f32x4 k1, f32x4 k2) {
  f32x4 r = v * k1 + k2;
  r.x = fmaxf(r.x, 0.f); r.y = fmaxf(r.y, 0.f);
  r.z = fmaxf(r.z, 0.f); r.w = fmaxf(r.w, 0.f);
  return r;
}

// reduce across the 4 16-lane groups (lanes l, l+16, l+32, l+48)
__device__ __forceinline__ f32x4 xreduce(f32x4 v) {
  v.x += __shfl_xor(v.x, 16); v.y += __shfl_xor(v.y, 16);
  v.z += __shfl_xor(v.z, 16); v.w += __shfl_xor(v.w, 16);
  v.x += __shfl_xor(v.x, 32); v.y += __shfl_xor(v.y, 32);
  v.z += __shfl_xor(v.z, 32); v.w += __shfl_xor(v.w, 32);
  return v;
}

__device__ __forceinline__ float bcast(float v, int lane) {
  return __int_as_float(__builtin_amdgcn_readlane(__float_as_int(v), lane));
}

// ---------------- setup kernels ----------------

__global__ void k_zero(int* __restrict__ cnt, float* __restrict__ sumP,
                       float* __restrict__ sumsqP, float* __restrict__ mstat,
                       int2* __restrict__ ewpad, int n) {
  int i = blockIdx.x * NTHREADS + threadIdx.x;
  if (i < n) cnt[i] = 0;
  if (i < 1024) { sumP[i] = 0.f; sumsqP[i] = 0.f; }
  if (i < 64) { mstat[i] = 1.f; mstat[64 + i] = 0.f; }  // identity BN for layer 0
  if (i < 16) ewpad[i] = make_int2(0, 0);               // tail-safe pad records
}

__global__ void k_hist(const int* __restrict__ col, int* __restrict__ cnt, int E) {
  int e = blockIdx.x * NTHREADS + threadIdx.x;
  if (e < E) atomicAdd(&cnt[col[e]], 1);
}

__global__ void k_dinv(const int* __restrict__ cnt, float* __restrict__ dinv, int n) {
  int i = blockIdx.x * NTHREADS + threadIdx.x;
  if (i < n) dinv[i] = rsqrtf((float)cnt[i] + 1.0f);
}

__global__ void k_scan1(const int* __restrict__ cnt, int* __restrict__ offs,
                        int* __restrict__ partials, int n) {
  __shared__ int sh[NTHREADS];
  int t = threadIdx.x, i = blockIdx.x * NTHREADS + t;
  int v = (i < n) ? cnt[i] : 0;
  sh[t] = v;
  __syncthreads();
  int run = v;
  for (int d = 1; d < NTHREADS; d <<= 1) {
    int add = (t >= d) ? sh[t - d] : 0;
    __syncthreads();
    run += add;
    sh[t] = run;
    __syncthreads();
  }
  if (i < n) offs[i] = run - v;
  if (t == NTHREADS - 1) partials[blockIdx.x] = run;
}

__global__ void k_scan2(int* __restrict__ partials, int nb) {
  __shared__ int sh[512];
  int t = threadIdx.x;
  int v = (t < nb) ? partials[t] : 0;
  sh[t] = v;
  __syncthreads();
  int run = v;
  for (int d = 1; d < 512; d <<= 1) {
    int add = (t >= d) ? sh[t - d] : 0;
    __syncthreads();
    run += add;
    sh[t] = run;
    __syncthreads();
  }
  if (t < nb) partials[t] = run - v;
}

__global__ void k_scan3(int* __restrict__ offs, int* __restrict__ cur,
                        const int* __restrict__ partials, int n, int E) {
  int i = blockIdx.x * NTHREADS + threadIdx.x;
  if (i < n) {
    int v = offs[i] + partials[i >> 8];
    offs[i] = v;
    cur[i] = v;
  }
  if (i == 0) offs[n] = E;
}

__global__ void k_fill(const int* __restrict__ row, const int* __restrict__ col,
                       const float* __restrict__ dinv, int* __restrict__ cur,
                       int2* __restrict__ ew, int E) {
  int e = blockIdx.x * NTHREADS + threadIdx.x;
  if (e < E) {
    int cl = col[e];
    int rw = row[e];
    int pos = atomicAdd(&cur[cl], 1);
    ew[pos] = make_int2(rw, __float_as_int(dinv[rw]));
  }
}

// ---------------- h0 = relu(x @ W0 + b0), fp16 out ----------------
__global__ __launch_bounds__(NTHREADS) void k_gemm0(
    const float* __restrict__ x, const float* __restrict__ W0,
    const float* __restrict__ b0, f16* __restrict__ h016, int n) {
  int t = threadIdx.x;
  int lane = t & 63;
  int c = lane;
  float Wc[IN_C];
#pragma unroll
  for (int k = 0; k < IN_C; k++) Wc[k] = W0[k * HID + c];
  float bias = b0[c];
  int half = lane >> 5, li = lane & 31;
  int wg = blockIdx.x * (NTHREADS / 64) + (t >> 6);
  int NW = gridDim.x * (NTHREADS / 64);
  int npairs = (n + 1) >> 1;
  for (int p = wg; p < npairs; p += NW) {
    int r = 2 * p + half;
    f32x4 xv = {0.f, 0.f, 0.f, 0.f};
    if (r < n) xv = ld4(x + (size_t)r * IN_C + li * 4);
    float acc0 = bias, acc1 = bias;
#pragma unroll
    for (int k = 0; k < IN_C; k++) {
      int sl = k >> 2;
      float comp = xv[k & 3];
      float a0 = bcast(comp, sl);
      float a1 = bcast(comp, 32 + sl);
      acc0 += a0 * Wc[k];
      acc1 += a1 * Wc[k];
    }
    acc0 = fmaxf(acc0, 0.f);
    acc1 = fmaxf(acc1, 0.f);
    if (2 * p < n)     h016[(size_t)(2 * p) * HID + c]     = (f16)acc0;
    if (2 * p + 1 < n) h016[(size_t)(2 * p + 1) * HID + c] = (f16)acc1;
  }
}

// ---------------- fused layer (fp16 h-streams, group-per-row) ----------------
// Each 16-lane group owns ONE row. Gather is a 16/8/4/scalar chunk cascade:
// the 16-deep chunk keeps 16 records + 16 payload lines in flight per group
// (64 lines/wave) and amortizes the two vmcnt drains over 16 edges.
// __launch_bounds__(256,4) pins VGPR <= 128 (the occupancy quantum cliff);
// r4/r5 showed any tighter cap spills loop state to scratch (WRITE blow-up).
#define CHUNK(D)                                                              \
  for (; j + D <= je; j += D) {                                               \
    long long q[D];                                                           \
    _Pragma("unroll") for (int k = 0; k < D; k++) q[k] = ew8[j + k];          \
    f16x4 u[D];                                                               \
    _Pragma("unroll") for (int k = 0; k < D; k++)                             \
        u[k] = *(const f16x4*)(hin + (size_t)(int)q[k] * HID + c4);           \
    _Pragma("unroll") for (int k = 0; k < D; k++)                             \
        acc += __int_as_float((int)(q[k] >> 32)) *                            \
               bnrelu(__builtin_convertvector(u[k], f32x4), k1, k2);          \
  }

__global__ __launch_bounds__(NTHREADS, 4) void k_layer(
    const f16* __restrict__ hin, const f16* __restrict__ h0,
    const float* __restrict__ dinv, const int* __restrict__ offs,
    const int2* __restrict__ ew, const float* __restrict__ Wl,
    const float* __restrict__ mstat, f16* __restrict__ sout,
    float* __restrict__ sumP, float* __restrict__ sumsqP, float beta, int n) {
  __shared__ __align__(16) float Wsh[HID * HID];  // 16 KB
  __shared__ f32x4 red4[2][4][16];                // 2 KB
  int t = threadIdx.x;
  for (int m = t; m < HID * HID / 4; m += NTHREADS)
    ((f32x4*)Wsh)[m] = ((const f32x4*)Wl)[m];
  int wid = t >> 6, lane = t & 63;
  int eg = lane >> 4, li = lane & 15, c4 = li << 2;
  f32x4 k1 = ld4(mstat + c4);
  f32x4 k2 = ld4(mstat + 64 + c4);
  __syncthreads();
  f32x4 lsum = {0.f, 0.f, 0.f, 0.f}, lsumsq = {0.f, 0.f, 0.f, 0.f};
  const long long* ew8 = (const long long*)ew;
  int stride = gridDim.x * 16;
  for (int base = blockIdx.x * 16; base < n; base += stride) {
    int i = base + wid * 4 + eg;   // this group's row
    bool act = (i < n);
    f32x4 sval = {0.f, 0.f, 0.f, 0.f};
    if (act) {
      int jb = offs[i], je = offs[i + 1];
      float di = dinv[i];
      f16x4 hs16 = *(const f16x4*)(hin + (size_t)i * HID + c4);
      f16x4 h016v = *(const f16x4*)(h0 + (size_t)i * HID + c4);
      f32x4 acc = {0.f, 0.f, 0.f, 0.f};
      int j = jb;
      CHUNK(16)
      CHUNK(8)
      CHUNK(4)
      for (; j < je; j++) {  // tail: 1..3 edges
        long long q = ew8[j];
        f32x4 v = ldh4(hin + (size_t)(int)q * HID + c4);
        acc += __int_as_float((int)(q >> 32)) * bnrelu(v, k1, k2);
      }
      f32x4 hs = bnrelu(__builtin_convertvector(hs16, f32x4), k1, k2);
      f32x4 h0v = __builtin_convertvector(h016v, f32x4);
      f32x4 agg = di * acc + (di * di) * hs;
      sval = (1.f - ALPHA) * agg + ALPHA * h0v;
    }
    // conv: all lanes execute (inactive groups carry sval=0, never stored)
    f32x4 ta = {0.f, 0.f, 0.f, 0.f};
#pragma unroll
    for (int k4 = 0; k4 < 16; k4++) {
      f32x4 s4;
      s4.x = __shfl(sval.x, k4, 16);
      s4.y = __shfl(sval.y, k4, 16);
      s4.z = __shfl(sval.z, k4, 16);
      s4.w = __shfl(sval.w, k4, 16);
      const f32x4* Wr = (const f32x4*)(Wsh + 4 * k4 * HID);
      ta += s4.x * Wr[li] + s4.y * Wr[16 + li] + s4.z * Wr[32 + li] +
            s4.w * Wr[48 + li];
    }
    f32x4 s2 = (1.f - beta) * sval + beta * ta;
    if (act) {
      lsum += s2;
      lsumsq += s2 * s2;
      f16x4 st = __builtin_convertvector(s2, f16x4);
      *(f16x4*)(sout + (size_t)i * HID + c4) = st;
    }
  }
  // cross-group reduce, then cross-wave via LDS
  lsum = xreduce(lsum);
  lsumsq = xreduce(lsumsq);
  if (eg == 0) { red4[0][wid][li] = lsum; red4[1][wid][li] = lsumsq; }
  __syncthreads();
  if (t < 16) {
    f32x4 a = red4[0][0][li] + red4[0][1][li] + red4[0][2][li] + red4[0][3][li];
    f32x4 b = red4[1][0][li] + red4[1][1][li] + red4[1][2][li] + red4[1][3][li];
    atomicAdd(&sumP[(c4 + 0) * 16], a.x);
    atomicAdd(&sumP[(c4 + 1) * 16], a.y);
    atomicAdd(&sumP[(c4 + 2) * 16], a.z);
    atomicAdd(&sumP[(c4 + 3) * 16], a.w);
    atomicAdd(&sumsqP[(c4 + 0) * 16], b.x);
    atomicAdd(&sumsqP[(c4 + 1) * 16], b.y);
    atomicAdd(&sumsqP[(c4 + 2) * 16], b.z);
    atomicAdd(&sumsqP[(c4 + 3) * 16], b.w);
  }
}

// mean/inv-std -> affine form k1 = iv*gamma, k2 = beta - mu*k1; resets sums
__global__ void k_finalize(float* __restrict__ sumP, float* __restrict__ sumsqP,
                           float* __restrict__ mstat,
                           const float* __restrict__ gamma_l,
                           const float* __restrict__ beta_l, int n) {
  int c = threadIdx.x;  // 64 threads
  float s = sumP[c * 16], sq = sumsqP[c * 16];
  float mu = s / (float)n;
  float var = sq / (float)n - mu * mu;
  float iv = rsqrtf(var + BN_EPS);
  float kk1 = iv * gamma_l[c];
  mstat[c] = kk1;
  mstat[64 + c] = beta_l[c] - mu * kk1;
  sumP[c * 16] = 0.f;
  sumsqP[c * 16] = 0.f;
}

// out = relu(BN(s)) @ W_out + b_out   (BN affine fused into the load)
__global__ __launch_bounds__(NTHREADS) void k_out(
    const f16* __restrict__ s, const float* __restrict__ mstat,
    const float* __restrict__ Wout, const float* __restrict__ bout,
    float* __restrict__ out, int n) {
  __shared__ float Ws[HID * OUT_C];
  __shared__ float bs[OUT_C];
  __shared__ __align__(16) float ms[128];
  int t = threadIdx.x;
  for (int m = t; m < HID * OUT_C; m += NTHREADS) Ws[m] = Wout[m];
  if (t < OUT_C) bs[t] = bout[t];
  if (t < 128) ms[t] = mstat[t];
  __syncthreads();
  int idx = blockIdx.x * NTHREADS + t;
  if (idx < n * OUT_C) {
    int row = idx / OUT_C;
    int c = idx - row * OUT_C;
    float acc = bs[c];
    const f16* sr = s + (size_t)row * HID;
    for (int kk = 0; kk < HID / 4; kk++) {
      f32x4 a = ldh4(sr + kk * 4);
      f32x4 k1 = *(const f32x4*)(ms + kk * 4);
      f32x4 k2 = *(const f32x4*)(ms + 64 + kk * 4);
      a = bnrelu(a, k1, k2);
      int k = kk * 4;
      acc += a.x * Ws[(k + 0) * OUT_C + c] + a.y * Ws[(k + 1) * OUT_C + c] +
             a.z * Ws[(k + 2) * OUT_C + c] + a.w * Ws[(k + 3) * OUT_C + c];
    }
    out[idx] = acc;
  }
}

// ---------------- host ----------------

extern "C" void kernel_launch(void* const* d_in, const int* in_sizes, int n_in,
                              void* d_out, int out_size, void* d_ws, size_t ws_size,
                              hipStream_t stream) {
  const float* x = (const float*)d_in[0];
  const int* ei = (const int*)d_in[1];
  const float* W0 = (const float*)d_in[2];
  const float* b0 = (const float*)d_in[3];
  const float* convW = (const float*)d_in[4];
  const float* bn_gamma = (const float*)d_in[5];
  const float* bn_beta = (const float*)d_in[6];
  const float* W_out = (const float*)d_in[7];
  const float* b_out = (const float*)d_in[8];
  float* out = (float*)d_out;

  int n = in_sizes[0] / IN_C;   // 100000
  int E = in_sizes[1] / 2;      // 1600000
  const int* row = ei;
  const int* col = ei + E;

  char* w = (char*)d_ws;
  auto alloc = [&](size_t bytes) {
    char* p = w;
    w += (bytes + 255) & ~(size_t)255;
    return p;
  };
  float* dinv    = (float*)alloc((size_t)n * 4);
  int*   cnt     = (int*)alloc((size_t)n * 4);
  int*   offs    = (int*)alloc((size_t)(n + 1) * 4);
  int*   cur     = (int*)alloc((size_t)n * 4);
  int*   partials= (int*)alloc(512 * 4);
  int2*  ew      = (int2*)alloc((size_t)(E + 16) * 8);  // +16 pad records
  f16*   h016    = (f16*)alloc((size_t)n * HID * 2);
  f16*   sA      = (f16*)alloc((size_t)n * HID * 2);
  f16*   sB      = (f16*)alloc((size_t)n * HID * 2);
  float* sumP    = (float*)alloc(1024 * 4);
  float* sumsqP  = (float*)alloc(1024 * 4);
  float* mstat   = (float*)alloc(128 * 4);

  int gN = (n + NTHREADS - 1) / NTHREADS;   // 391
  int gE = (E + NTHREADS - 1) / NTHREADS;   // 6250

  k_zero<<<gN, NTHREADS, 0, stream>>>(cnt, sumP, sumsqP, mstat, ew + E, n);
  k_hist<<<gE, NTHREADS, 0, stream>>>(col, cnt, E);
  k_dinv<<<gN, NTHREADS, 0, stream>>>(cnt, dinv, n);
  k_scan1<<<gN, NTHREADS, 0, stream>>>(cnt, offs, partials, n);
  k_scan2<<<1, 512, 0, stream>>>(partials, gN);
  k_scan3<<<gN, NTHREADS, 0, stream>>>(offs, cur, partials, n, E);
  k_fill<<<gE, NTHREADS, 0, stream>>>(row, col, dinv, cur, ew, E);

  k_gemm0<<<1024, NTHREADS, 0, stream>>>(x, W0, b0, h016, n);

  // layer l: input = (l==0 ? h016 : previous out), BN_{l-1} fused via mstat
  for (int l = 0; l < N_LAYERS; l++) {
    float beta = logf(0.5f / (float)(l + 1) + 1.0f);
    const f16* inp = (l == 0) ? h016 : ((l & 1) ? sA : sB);
    f16* outp = (l & 1) ? sB : sA;
    k_layer<<<2048, NTHREADS, 0, stream>>>(inp, h016, dinv, offs, ew,
                                           convW + (size_t)l * HID * HID, mstat,
                                           outp, sumP, sumsqP, beta, n);
    k_finalize<<<1, 64, 0, stream>>>(sumP, sumsqP, mstat,
                                     bn_gamma + l * HID, bn_beta + l * HID, n);
  }

  // s_7 lives in sB; k_out applies BN_7 + relu inline, then output GEMM
  k_out<<<((size_t)n * OUT_C + NTHREADS - 1) / NTHREADS, NTHREADS, 0, stream>>>(
      sB, mstat, W_out, b_out, out, n);
}

// Round 8
// 1276.310 us; speedup vs baseline: 1.2576x; 1.2576x over previous
//
#include <hip/hip_runtime.h>
#include <math.h>

#define NTHREADS 256
#define IN_C 128
#define HID 64
#define OUT_C 40
#define N_LAYERS 8
#define ALPHA 0.1f
#define BN_EPS 1e-5f

typedef float f32x4 __attribute__((ext_vector_type(4)));
typedef _Float16 f16;
typedef _Float16 f16x4 __attribute__((ext_vector_type(4)));

__device__ __forceinline__ f32x4 ld4(const float* p) { return *(const f32x4*)p; }

// fp16 row load + widen
__device__ __forceinline__ f32x4 ldh4(const f16* p) {
  f16x4 v = *(const f16x4*)p;
  return __builtin_convertvector(v, f32x4);
}

// fused BN + ReLU: relu(v*k1 + k2)
__device__ __forceinline__ f32x4 bnrelu(f32x4 v, f32x4 k1, f32x4 k2) {
  f32x4 r = v * k1 + k2;
  r.x = fmaxf(r.x, 0.f); r.y = fmaxf(r.y, 0.f);
  r.z = fmaxf(r.z, 0.f); r.w = fmaxf(r.w, 0.f);
  return r;
}

// reduce across the 4 16-lane groups (lanes l, l+16, l+32, l+48)
__device__ __forceinline__ f32x4 xreduce(f32x4 v) {
  v.x += __shfl_xor(v.x, 16); v.y += __shfl_xor(v.y, 16);
  v.z += __shfl_xor(v.z, 16); v.w += __shfl_xor(v.w, 16);
  v.x += __shfl_xor(v.x, 32); v.y += __shfl_xor(v.y, 32);
  v.z += __shfl_xor(v.z, 32); v.w += __shfl_xor(v.w, 32);
  return v;
}

__device__ __forceinline__ float bcast(float v, int lane) {
  return __int_as_float(__builtin_amdgcn_readlane(__float_as_int(v), lane));
}

// ---------------- setup kernels ----------------

__global__ void k_zero(int* __restrict__ cnt, float* __restrict__ sumP,
                       float* __restrict__ sumsqP, float* __restrict__ mstat,
                       int2* __restrict__ ewpad, int n) {
  int i = blockIdx.x * NTHREADS + threadIdx.x;
  if (i < n) cnt[i] = 0;
  if (i < 1024) { sumP[i] = 0.f; sumsqP[i] = 0.f; }
  if (i < 64) { mstat[i] = 1.f; mstat[64 + i] = 0.f; }
  if (i < 16) ewpad[i] = make_int2(0, 0);
}

__global__ void k_hist(const int* __restrict__ col, int* __restrict__ cnt, int E) {
  int e = blockIdx.x * NTHREADS + threadIdx.x;
  if (e < E) atomicAdd(&cnt[col[e]], 1);
}

__global__ void k_dinv(const int* __restrict__ cnt, float* __restrict__ dinv, int n) {
  int i = blockIdx.x * NTHREADS + threadIdx.x;
  if (i < n) dinv[i] = rsqrtf((float)cnt[i] + 1.0f);
}

__global__ void k_scan1(const int* __restrict__ cnt, int* __restrict__ offs,
                        int* __restrict__ partials, int n) {
  __shared__ int sh[NTHREADS];
  int t = threadIdx.x, i = blockIdx.x * NTHREADS + t;
  int v = (i < n) ? cnt[i] : 0;
  sh[t] = v;
  __syncthreads();
  int run = v;
  for (int d = 1; d < NTHREADS; d <<= 1) {
    int add = (t >= d) ? sh[t - d] : 0;
    __syncthreads();
    run += add;
    sh[t] = run;
    __syncthreads();
  }
  if (i < n) offs[i] = run - v;
  if (t == NTHREADS - 1) partials[blockIdx.x] = run;
}

__global__ void k_scan2(int* __restrict__ partials, int nb) {
  __shared__ int sh[512];
  int t = threadIdx.x;
  int v = (t < nb) ? partials[t] : 0;
  sh[t] = v;
  __syncthreads();
  int run = v;
  for (int d = 1; d < 512; d <<= 1) {
    int add = (t >= d) ? sh[t - d] : 0;
    __syncthreads();
    run += add;
    sh[t] = run;
    __syncthreads();
  }
  if (t < nb) partials[t] = run - v;
}

__global__ void k_scan3(int* __restrict__ offs, int* __restrict__ cur,
                        const int* __restrict__ partials, int n, int E) {
  int i = blockIdx.x * NTHREADS + threadIdx.x;
  if (i < n) {
    int v = offs[i] + partials[i >> 8];
    offs[i] = v;
    cur[i] = v;
  }
  if (i == 0) offs[n] = E;
}

__global__ void k_fill(const int* __restrict__ row, const int* __restrict__ col,
                       const float* __restrict__ dinv, int* __restrict__ cur,
                       int2* __restrict__ ew, int E) {
  int e = blockIdx.x * NTHREADS + threadIdx.x;
  if (e < E) {
    int cl = col[e];
    int rw = row[e];
    int pos = atomicAdd(&cur[cl], 1);
    ew[pos] = make_int2(rw, __float_as_int(dinv[rw]));
  }
}

// ---------------- h0 = relu(x @ W0 + b0), fp16 out ----------------
__global__ __launch_bounds__(NTHREADS) void k_gemm0(
    const float* __restrict__ x, const float* __restrict__ W0,
    const float* __restrict__ b0, f16* __restrict__ h016, int n) {
  int t = threadIdx.x;
  int lane = t & 63;
  int c = lane;
  float Wc[IN_C];
#pragma unroll
  for (int k = 0; k < IN_C; k++) Wc[k] = W0[k * HID + c];
  float bias = b0[c];
  int half = lane >> 5, li = lane & 31;
  int wg = blockIdx.x * (NTHREADS / 64) + (t >> 6);
  int NW = gridDim.x * (NTHREADS / 64);
  int npairs = (n + 1) >> 1;
  for (int p = wg; p < npairs; p += NW) {
    int r = 2 * p + half;
    f32x4 xv = {0.f, 0.f, 0.f, 0.f};
    if (r < n) xv = ld4(x + (size_t)r * IN_C + li * 4);
    float acc0 = bias, acc1 = bias;
#pragma unroll
    for (int k = 0; k < IN_C; k++) {
      int sl = k >> 2;
      float comp = xv[k & 3];
      float a0 = bcast(comp, sl);
      float a1 = bcast(comp, 32 + sl);
      acc0 += a0 * Wc[k];
      acc1 += a1 * Wc[k];
    }
    acc0 = fmaxf(acc0, 0.f);
    acc1 = fmaxf(acc1, 0.f);
    if (2 * p < n)     h016[(size_t)(2 * p) * HID + c]     = (f16)acc0;
    if (2 * p + 1 < n) h016[(size_t)(2 * p + 1) * HID + c] = (f16)acc1;
  }
}

// ---------------- gather-only kernel ----------------
// sv[i] = (1-a)*(di*acc + di^2*hp[i]) + a*h0[i],  acc = sum_j w_j * hp[src_j]
// One 16-lane group per row; 8-deep chunks; NO LDS, NO barriers, NO W, NO
// stats, NO BN (hp is pre-activated) -> ~60 VGPR naturally, high occupancy
// AND 32 lines in flight per wave. No launch_bounds cap (r4/r5/r7: any tight
// cap makes the allocator spill loop state to scratch -> WRITE blow-up).
__global__ void k_gather(
    const f16* __restrict__ hp, const f16* __restrict__ h0,
    const float* __restrict__ dinv, const int* __restrict__ offs,
    const int2* __restrict__ ew, f16* __restrict__ sv, int n) {
  int t = threadIdx.x;
  int lane = t & 63;
  int eg = lane >> 4, li = lane & 15, c4 = li << 2;
  int i = blockIdx.x * 16 + (t >> 6) * 4 + eg;  // this group's row
  if (i >= n) return;
  int jb = offs[i], je = offs[i + 1];
  float di = dinv[i];
  f16x4 hs16 = *(const f16x4*)(hp + (size_t)i * HID + c4);
  f16x4 h016v = *(const f16x4*)(h0 + (size_t)i * HID + c4);
  f32x4 acc = {0.f, 0.f, 0.f, 0.f};
  const long long* ew8 = (const long long*)ew;
  int j = jb;
  for (; j + 8 <= je; j += 8) {
    long long q0 = ew8[j + 0];
    long long q1 = ew8[j + 1];
    long long q2 = ew8[j + 2];
    long long q3 = ew8[j + 3];
    long long q4 = ew8[j + 4];
    long long q5 = ew8[j + 5];
    long long q6 = ew8[j + 6];
    long long q7 = ew8[j + 7];
    f16x4 u0 = *(const f16x4*)(hp + (size_t)(int)q0 * HID + c4);
    f16x4 u1 = *(const f16x4*)(hp + (size_t)(int)q1 * HID + c4);
    f16x4 u2 = *(const f16x4*)(hp + (size_t)(int)q2 * HID + c4);
    f16x4 u3 = *(const f16x4*)(hp + (size_t)(int)q3 * HID + c4);
    f16x4 u4 = *(const f16x4*)(hp + (size_t)(int)q4 * HID + c4);
    f16x4 u5 = *(const f16x4*)(hp + (size_t)(int)q5 * HID + c4);
    f16x4 u6 = *(const f16x4*)(hp + (size_t)(int)q6 * HID + c4);
    f16x4 u7 = *(const f16x4*)(hp + (size_t)(int)q7 * HID + c4);
    acc += __int_as_float((int)(q0 >> 32)) * __builtin_convertvector(u0, f32x4);
    acc += __int_as_float((int)(q1 >> 32)) * __builtin_convertvector(u1, f32x4);
    acc += __int_as_float((int)(q2 >> 32)) * __builtin_convertvector(u2, f32x4);
    acc += __int_as_float((int)(q3 >> 32)) * __builtin_convertvector(u3, f32x4);
    acc += __int_as_float((int)(q4 >> 32)) * __builtin_convertvector(u4, f32x4);
    acc += __int_as_float((int)(q5 >> 32)) * __builtin_convertvector(u5, f32x4);
    acc += __int_as_float((int)(q6 >> 32)) * __builtin_convertvector(u6, f32x4);
    acc += __int_as_float((int)(q7 >> 32)) * __builtin_convertvector(u7, f32x4);
  }
  for (; j < je; j++) {
    long long q = ew8[j];
    acc += __int_as_float((int)(q >> 32)) *
           ldh4(hp + (size_t)(int)q * HID + c4);
  }
  f32x4 hs = __builtin_convertvector(hs16, f32x4);
  f32x4 h0v = __builtin_convertvector(h016v, f32x4);
  f32x4 agg = di * acc + (di * di) * hs;
  f32x4 sval = (1.f - ALPHA) * agg + ALPHA * h0v;
  *(f16x4*)(sv + (size_t)i * HID + c4) = __builtin_convertvector(sval, f16x4);
}

// ---------------- streaming conv + BN stats ----------------
// s = (1-beta)*sv + beta*(sv @ W); accumulate per-channel sum/sumsq of s.
// Fully coalesced; shuffle-broadcast conv (one 16-lane group per row).
__global__ __launch_bounds__(NTHREADS) void k_conv(
    const f16* __restrict__ sv, const float* __restrict__ Wl,
    f16* __restrict__ sout, float* __restrict__ sumP,
    float* __restrict__ sumsqP, float beta, int n) {
  __shared__ __align__(16) float Wsh[HID * HID];  // 16 KB
  __shared__ f32x4 red4[2][4][16];                // 2 KB
  int t = threadIdx.x;
  for (int m = t; m < HID * HID / 4; m += NTHREADS)
    ((f32x4*)Wsh)[m] = ((const f32x4*)Wl)[m];
  int wid = t >> 6, lane = t & 63;
  int eg = lane >> 4, li = lane & 15, c4 = li << 2;
  __syncthreads();
  f32x4 lsum = {0.f, 0.f, 0.f, 0.f}, lsumsq = {0.f, 0.f, 0.f, 0.f};
  int stride = gridDim.x * 16;
  for (int base = blockIdx.x * 16; base < n; base += stride) {
    int i = base + wid * 4 + eg;
    bool act = (i < n);
    f32x4 sval = {0.f, 0.f, 0.f, 0.f};
    if (act) sval = ldh4(sv + (size_t)i * HID + c4);
    f32x4 ta = {0.f, 0.f, 0.f, 0.f};
#pragma unroll
    for (int k4 = 0; k4 < 16; k4++) {
      f32x4 s4;
      s4.x = __shfl(sval.x, k4, 16);
      s4.y = __shfl(sval.y, k4, 16);
      s4.z = __shfl(sval.z, k4, 16);
      s4.w = __shfl(sval.w, k4, 16);
      const f32x4* Wr = (const f32x4*)(Wsh + 4 * k4 * HID);
      ta += s4.x * Wr[li] + s4.y * Wr[16 + li] + s4.z * Wr[32 + li] +
            s4.w * Wr[48 + li];
    }
    f32x4 s2 = (1.f - beta) * sval + beta * ta;
    if (act) {
      lsum += s2;
      lsumsq += s2 * s2;
      *(f16x4*)(sout + (size_t)i * HID + c4) = __builtin_convertvector(s2, f16x4);
    }
  }
  lsum = xreduce(lsum);
  lsumsq = xreduce(lsumsq);
  if (eg == 0) { red4[0][wid][li] = lsum; red4[1][wid][li] = lsumsq; }
  __syncthreads();
  if (t < 16) {
    f32x4 a = red4[0][0][li] + red4[0][1][li] + red4[0][2][li] + red4[0][3][li];
    f32x4 b = red4[1][0][li] + red4[1][1][li] + red4[1][2][li] + red4[1][3][li];
    atomicAdd(&sumP[(c4 + 0) * 16], a.x);
    atomicAdd(&sumP[(c4 + 1) * 16], a.y);
    atomicAdd(&sumP[(c4 + 2) * 16], a.z);
    atomicAdd(&sumP[(c4 + 3) * 16], a.w);
    atomicAdd(&sumsqP[(c4 + 0) * 16], b.x);
    atomicAdd(&sumsqP[(c4 + 1) * 16], b.y);
    atomicAdd(&sumsqP[(c4 + 2) * 16], b.z);
    atomicAdd(&sumsqP[(c4 + 3) * 16], b.w);
  }
}

// mean/inv-std -> affine form k1 = iv*gamma, k2 = beta - mu*k1; resets sums
__global__ void k_finalize(float* __restrict__ sumP, float* __restrict__ sumsqP,
                           float* __restrict__ mstat,
                           const float* __restrict__ gamma_l,
                           const float* __restrict__ beta_l, int n) {
  int c = threadIdx.x;  // 64 threads
  float s = sumP[c * 16], sq = sumsqP[c * 16];
  float mu = s / (float)n;
  float var = sq / (float)n - mu * mu;
  float iv = rsqrtf(var + BN_EPS);
  float kk1 = iv * gamma_l[c];
  mstat[c] = kk1;
  mstat[64 + c] = beta_l[c] - mu * kk1;
  sumP[c * 16] = 0.f;
  sumsqP[c * 16] = 0.f;
}

// hp = relu(s*k1 + k2): fp16 in, fp16 out (pre-activated gather operand)
__global__ void k_bnrelu(const f16* __restrict__ s,
                         const float* __restrict__ mstat,
                         f16* __restrict__ hp, int n) {
  int idx = blockIdx.x * NTHREADS + threadIdx.x;  // x4 index
  if (idx < n * (HID / 4)) {
    int c4 = idx & 15;
    f32x4 v = ldh4(s + (size_t)idx * 4);
    f32x4 k1 = ((const f32x4*)mstat)[c4];
    f32x4 k2 = ((const f32x4*)(mstat + 64))[c4];
    v = bnrelu(v, k1, k2);
    ((f16x4*)hp)[idx] = __builtin_convertvector(v, f16x4);
  }
}

// out = relu(BN(s)) @ W_out + b_out   (BN affine fused into the load)
__global__ __launch_bounds__(NTHREADS) void k_out(
    const f16* __restrict__ s, const float* __restrict__ mstat,
    const float* __restrict__ Wout, const float* __restrict__ bout,
    float* __restrict__ out, int n) {
  __shared__ float Ws[HID * OUT_C];
  __shared__ float bs[OUT_C];
  __shared__ __align__(16) float ms[128];
  int t = threadIdx.x;
  for (int m = t; m < HID * OUT_C; m += NTHREADS) Ws[m] = Wout[m];
  if (t < OUT_C) bs[t] = bout[t];
  if (t < 128) ms[t] = mstat[t];
  __syncthreads();
  int idx = blockIdx.x * NTHREADS + t;
  if (idx < n * OUT_C) {
    int row = idx / OUT_C;
    int c = idx - row * OUT_C;
    float acc = bs[c];
    const f16* sr = s + (size_t)row * HID;
    for (int kk = 0; kk < HID / 4; kk++) {
      f32x4 a = ldh4(sr + kk * 4);
      f32x4 k1 = *(const f32x4*)(ms + kk * 4);
      f32x4 k2 = *(const f32x4*)(ms + 64 + kk * 4);
      a = bnrelu(a, k1, k2);
      int k = kk * 4;
      acc += a.x * Ws[(k + 0) * OUT_C + c] + a.y * Ws[(k + 1) * OUT_C + c] +
             a.z * Ws[(k + 2) * OUT_C + c] + a.w * Ws[(k + 3) * OUT_C + c];
    }
    out[idx] = acc;
  }
}

// ---------------- host ----------------

extern "C" void kernel_launch(void* const* d_in, const int* in_sizes, int n_in,
                              void* d_out, int out_size, void* d_ws, size_t ws_size,
                              hipStream_t stream) {
  const float* x = (const float*)d_in[0];
  const int* ei = (const int*)d_in[1];
  const float* W0 = (const float*)d_in[2];
  const float* b0 = (const float*)d_in[3];
  const float* convW = (const float*)d_in[4];
  const float* bn_gamma = (const float*)d_in[5];
  const float* bn_beta = (const float*)d_in[6];
  const float* W_out = (const float*)d_in[7];
  const float* b_out = (const float*)d_in[8];
  float* out = (float*)d_out;

  int n = in_sizes[0] / IN_C;   // 100000
  int E = in_sizes[1] / 2;      // 1600000
  const int* row = ei;
  const int* col = ei + E;

  char* w = (char*)d_ws;
  auto alloc = [&](size_t bytes) {
    char* p = w;
    w += (bytes + 255) & ~(size_t)255;
    return p;
  };
  float* dinv    = (float*)alloc((size_t)n * 4);
  int*   cnt     = (int*)alloc((size_t)n * 4);
  int*   offs    = (int*)alloc((size_t)(n + 1) * 4);
  int*   cur     = (int*)alloc((size_t)n * 4);
  int*   partials= (int*)alloc(512 * 4);
  int2*  ew      = (int2*)alloc((size_t)(E + 16) * 8);  // +16 pad records
  f16*   h016    = (f16*)alloc((size_t)n * HID * 2);
  f16*   hp      = (f16*)alloc((size_t)n * HID * 2);    // relu(BN(s_{l-1}))
  f16*   sv      = (f16*)alloc((size_t)n * HID * 2);    // gather output
  f16*   sb      = (f16*)alloc((size_t)n * HID * 2);    // conv output s_l
  float* sumP    = (float*)alloc(1024 * 4);
  float* sumsqP  = (float*)alloc(1024 * 4);
  float* mstat   = (float*)alloc(128 * 4);

  int gN = (n + NTHREADS - 1) / NTHREADS;   // 391
  int gE = (E + NTHREADS - 1) / NTHREADS;   // 6250
  int gRow = (n + 15) / 16;                 // 6250: one block per 16 rows

  k_zero<<<gN, NTHREADS, 0, stream>>>(cnt, sumP, sumsqP, mstat, ew + E, n);
  k_hist<<<gE, NTHREADS, 0, stream>>>(col, cnt, E);
  k_dinv<<<gN, NTHREADS, 0, stream>>>(cnt, dinv, n);
  k_scan1<<<gN, NTHREADS, 0, stream>>>(cnt, offs, partials, n);
  k_scan2<<<1, 512, 0, stream>>>(partials, gN);
  k_scan3<<<gN, NTHREADS, 0, stream>>>(offs, cur, partials, n, E);
  k_fill<<<gE, NTHREADS, 0, stream>>>(row, col, dinv, cur, ew, E);

  k_gemm0<<<1024, NTHREADS, 0, stream>>>(x, W0, b0, h016, n);

  for (int l = 0; l < N_LAYERS; l++) {
    float beta = logf(0.5f / (float)(l + 1) + 1.0f);
    const f16* src = h016;
    if (l > 0) {  // hp = relu(BN_{l-1}(s_{l-1}))
      k_bnrelu<<<(n * (HID / 4) + NTHREADS - 1) / NTHREADS, NTHREADS, 0, stream>>>(
          sb, mstat, hp, n);
      src = hp;
    }
    k_gather<<<gRow, NTHREADS, 0, stream>>>(src, h016, dinv, offs, ew, sv, n);
    k_conv<<<2048, NTHREADS, 0, stream>>>(sv, convW + (size_t)l * HID * HID,
                                          sb, sumP, sumsqP, beta, n);
    k_finalize<<<1, 64, 0, stream>>>(sumP, sumsqP, mstat,
                                     bn_gamma + l * HID, bn_beta + l * HID, n);
  }

  // s_7 in sb; k_out applies BN_7 + relu inline, then output GEMM
  k_out<<<((size_t)n * OUT_C + NTHREADS - 1) / NTHREADS, NTHREADS, 0, stream>>>(
      sb, mstat, W_out, b_out, out, n);
}